// Round 1
// baseline (383.039 us; speedup 1.0000x reference)
//
#include <hip/hip_runtime.h>
#include <hip/hip_bf16.h>

// Problem constants
#define B_  4096
#define T_  80
#define E_  100
#define U_  64
#define G_  256    // 4*U
#define V_  10000

#define XK_STRIDE 260   // floats per row in xk/z LDS buffers (16B-aligned, padded)
#define H_STRIDE  72    // bf16 elements per row in h LDS (padded)

typedef __attribute__((ext_vector_type(8))) __bf16 bf16x8;
typedef __attribute__((ext_vector_type(4))) float  floatx4;

__device__ __forceinline__ float sigmoidf_(float x) {
    float e = __expf(-x);
    return __fdividef(1.f, 1.f + e);
}

__device__ __forceinline__ float tanhf_(float x) {
    // safe tanh via exp of non-negative arg (no inf/inf NaN)
    float ax = fabsf(x);
    float e  = __expf(2.f * ax);
    float r  = 1.f - __fdividef(2.f, e + 1.f);
    return copysignf(r, x);
}

// ---------------------------------------------------------------------------
// Kernel A: embk[v][g] = b1[g] + sum_e emb[v][e] * k1[e][g]
// One block = 16 vocab rows; k1 column cached in VGPRs; emb row reads are
// block-uniform -> scalar loads.
// ---------------------------------------------------------------------------
__global__ __launch_bounds__(256) void embk_kernel(const float* __restrict__ emb,
                                                   const float* __restrict__ k1,
                                                   const float* __restrict__ b1,
                                                   float* __restrict__ embk) {
    const int g  = threadIdx.x;      // 0..255 gate column
    const int v0 = blockIdx.x * 16;

    float kcol[E_];
#pragma unroll
    for (int e = 0; e < E_; ++e) kcol[e] = k1[e * G_ + g];
    const float bias = b1[g];

    for (int r = 0; r < 16; ++r) {
        const int v = v0 + r;
        const float* __restrict__ erow = emb + (long)v * E_;
        float acc = bias;
#pragma unroll
        for (int e = 0; e < E_; ++e) acc = fmaf(erow[e], kcol[e], acc);
        embk[(long)v * G_ + g] = acc;
    }
}

// ---------------------------------------------------------------------------
// Kernel B: the recurrence. One block = 16 batch rows, all 80 timesteps.
// z[16x256] = h[16x64](bf16) @ r1[64x256](bf16, in VGPRs) + embk[tok] (fp32)
// ---------------------------------------------------------------------------
__global__ __launch_bounds__(256) void lstm_kernel(const int*   __restrict__ tokens,
                                                   const float* __restrict__ embk,
                                                   const float* __restrict__ r1,
                                                   const float* __restrict__ Wd,
                                                   const float* __restrict__ bd,
                                                   float* __restrict__ out) {
    __shared__ int    tokLDS[16 * T_];
    __shared__ __bf16 hLDS[16 * H_STRIDE];
    __shared__ float  xkLDS[16 * XK_STRIDE];
    __shared__ float  zLDS[16 * XK_STRIDE];

    const int tid  = threadIdx.x;
    const int lane = tid & 63;
    const int wv   = tid >> 6;          // wave id 0..3: owns gate-cols [wv*64, wv*64+64)
    const int bb   = blockIdx.x * 16;   // batch base

    // --- preload tokens for this batch tile (rows contiguous in memory) ---
    for (int i = tid; i < 16 * T_; i += 256) tokLDS[i] = tokens[bb * T_ + i];

    // --- zero h state in LDS ---
    for (int i = tid; i < 16 * H_STRIDE; i += 256) hLDS[i] = (__bf16)0.f;

    // --- preload r1 B-fragments into VGPRs (bf16), held for entire T loop ---
    // B[k][n] fragment: n = lane&15 (+tile col base), k = (lane>>4)*8 + j
    bf16x8 bfr[2][4];
    {
        const int kg = lane >> 4;
        const int nn = lane & 15;
#pragma unroll
        for (int kc = 0; kc < 2; ++kc)
#pragma unroll
            for (int ct = 0; ct < 4; ++ct) {
                bf16x8 s;
#pragma unroll
                for (int j = 0; j < 8; ++j) {
                    int k   = kc * 32 + kg * 8 + j;
                    int col = (wv << 6) + ct * 16 + nn;
                    s[j] = (__bf16)r1[k * G_ + col];
                }
                bfr[kc][ct] = s;
            }
    }

    // per-thread cell state: b = wv + 4*i, u = lane
    float c[4] = {0.f, 0.f, 0.f, 0.f};
    float h[4] = {0.f, 0.f, 0.f, 0.f};

    __syncthreads();

    // --- xk gather assignment: row = tid>>4 (16 rows), chunk = tid&15 ---
    const int row   = tid >> 4;
    const int chunk = tid & 15;
    float4 xr[4];
    {
        const int tok = tokLDS[row * T_ + 0];
        const float* rb = embk + (long)tok * G_;
#pragma unroll
        for (int k = 0; k < 4; ++k)
            xr[k] = *(const float4*)(rb + (k * 16 + chunk) * 4);
    }

    for (int t = 0; t < T_; ++t) {
        // stage this step's xk into LDS
#pragma unroll
        for (int k = 0; k < 4; ++k)
            *(float4*)(xkLDS + row * XK_STRIDE + (k * 16 + chunk) * 4) = xr[k];

        __syncthreads();   // xkLDS + hLDS(h_{t-1}) visible

        // prefetch next step's xk (issued early; MFMA phase hides latency)
        {
            const int tn  = (t + 1 < T_) ? (t + 1) : t;
            const int tok = tokLDS[row * T_ + tn];
            const float* rb = embk + (long)tok * G_;
#pragma unroll
            for (int k = 0; k < 4; ++k)
                xr[k] = *(const float4*)(rb + (k * 16 + chunk) * 4);
        }

        // ---- MFMA phase: z = h @ r1 + xk ----
        {
            const int m  = lane & 15;
            const int kg = lane >> 4;
            bf16x8 a0 = *(const bf16x8*)(hLDS + m * H_STRIDE + kg * 8);
            bf16x8 a1 = *(const bf16x8*)(hLDS + m * H_STRIDE + 32 + kg * 8);
#pragma unroll
            for (int ct = 0; ct < 4; ++ct) {
                floatx4 acc = {0.f, 0.f, 0.f, 0.f};
                acc = __builtin_amdgcn_mfma_f32_16x16x32_bf16(a0, bfr[0][ct], acc, 0, 0, 0);
                acc = __builtin_amdgcn_mfma_f32_16x16x32_bf16(a1, bfr[1][ct], acc, 0, 0, 0);
                const int col = (wv << 6) + ct * 16 + m;
#pragma unroll
                for (int r = 0; r < 4; ++r) {
                    const int brow = kg * 4 + r;   // C/D: row=(lane>>4)*4+reg, col=lane&15
                    float z = acc[r] + xkLDS[brow * XK_STRIDE + col];
                    zLDS[brow * XK_STRIDE + col] = z;
                }
            }
        }
        __syncthreads();   // zLDS ready (all gate columns from all waves)

        // ---- update phase: 4 cells per thread (b = wv+4i, u = lane) ----
#pragma unroll
        for (int i = 0; i < 4; ++i) {
            const int b = wv + 4 * i;
            const float* zb = zLDS + b * XK_STRIDE;
            float zi = zb[lane];
            float zf = zb[64 + lane];
            float zg = zb[128 + lane];
            float zo = zb[192 + lane];
            float cn = sigmoidf_(zf) * c[i] + sigmoidf_(zi) * tanhf_(zg);
            float hn = sigmoidf_(zo) * tanhf_(cn);
            c[i] = cn;
            h[i] = hn;
            hLDS[b * H_STRIDE + lane] = (__bf16)hn;   // read next step after barrier
        }
        // no barrier here: next iteration's first __syncthreads covers h/xk hazards
    }

    // ---- output: out[b] = sigmoid(h[b] . Wd + bd) ----
    const float wd  = Wd[lane];
    const float bdv = bd[0];
#pragma unroll
    for (int i = 0; i < 4; ++i) {
        float v = h[i] * wd;
#pragma unroll
        for (int off = 32; off > 0; off >>= 1) v += __shfl_down(v, off);
        if (lane == 0) out[bb + wv + 4 * i] = sigmoidf_(v + bdv);
    }
}

// ---------------------------------------------------------------------------
extern "C" void kernel_launch(void* const* d_in, const int* in_sizes, int n_in,
                              void* d_out, int out_size, void* d_ws, size_t ws_size,
                              hipStream_t stream) {
    const int*   tokens = (const int*)  d_in[0];
    const float* emb    = (const float*)d_in[1];
    // d_in[2..4] = k0, r0, b0 : dead code in the reference (cell 0 never feeds output)
    const float* k1     = (const float*)d_in[5];
    const float* r1     = (const float*)d_in[6];
    const float* b1     = (const float*)d_in[7];
    const float* Wd     = (const float*)d_in[8];
    const float* bd     = (const float*)d_in[9];
    float*       out    = (float*)d_out;

    float* embk = (float*)d_ws;   // V_*G_ floats = 10.24 MB

    embk_kernel<<<V_ / 16, 256, 0, stream>>>(emb, k1, b1, embk);
    lstm_kernel<<<B_ / 16, 256, 0, stream>>>(tokens, embk, r1, Wd, bd, out);
}

// Round 2
// 213.265 us; speedup vs baseline: 1.7961x; 1.7961x over previous
//
#include <hip/hip_runtime.h>
#include <hip/hip_bf16.h>

// Problem constants
#define B_  4096
#define T_  80
#define E_  100
#define U_  64
#define G_  256    // 4*U
#define V_  10000

#define S_H 72     // h LDS row stride (bf16 elems): %8==0 for b128 alignment, padded vs 64

typedef __attribute__((ext_vector_type(8))) __bf16 bf16x8;
typedef __attribute__((ext_vector_type(4))) float  floatx4;

__device__ __forceinline__ float sigmoidf_(float x) {
    float e = __expf(-x);
    return __fdividef(1.f, 1.f + e);
}

__device__ __forceinline__ float tanhf_(float x) {
    float ax = fabsf(x);
    float e  = __expf(2.f * ax);
    float r  = 1.f - __fdividef(2.f, e + 1.f);
    return copysignf(r, x);
}

// ---------------------------------------------------------------------------
// Kernel A: embk[v][g] = b1[g] + emb[v] . k1[:,g]
// 64 vocab rows per block; emb rows staged in LDS, broadcast float4 reads;
// k1 column held in VGPRs. fma-bound.
// ---------------------------------------------------------------------------
__global__ __launch_bounds__(256) void embk_kernel(const float* __restrict__ emb,
                                                   const float* __restrict__ k1,
                                                   const float* __restrict__ b1,
                                                   float* __restrict__ embk) {
    __shared__ float eLDS[64 * E_];          // 25.6 KB
    const int g  = threadIdx.x;              // gate column 0..255
    const int v0 = blockIdx.x * 64;
    const int nrows = min(64, V_ - v0);

    float kcol[E_];
#pragma unroll
    for (int e = 0; e < E_; ++e) kcol[e] = k1[e * G_ + g];
    const float bias = b1[g];

    for (int i = g; i < nrows * E_; i += 256) eLDS[i] = emb[(long)v0 * E_ + i];
    __syncthreads();

    for (int rb = 0; rb < 4; ++rb) {
        if (rb * 16 >= nrows) break;
        for (int r = 0; r < 16; ++r) {
            const int v = v0 + rb * 16 + r;
            if (v >= V_) break;
            const float* er = eLDS + (rb * 16 + r) * E_;
            float a = bias;
#pragma unroll
            for (int e4 = 0; e4 < E_ / 4; ++e4) {
                float4 ev = *(const float4*)(er + e4 * 4);
                a = fmaf(ev.x, kcol[4 * e4 + 0], a);
                a = fmaf(ev.y, kcol[4 * e4 + 1], a);
                a = fmaf(ev.z, kcol[4 * e4 + 2], a);
                a = fmaf(ev.w, kcol[4 * e4 + 3], a);
            }
            embk[(long)v * G_ + g] = a;
        }
    }
}

// ---------------------------------------------------------------------------
// Kernel B: recurrence. Block = 16 batch rows, 4 waves; wave w owns units
// [w*16, w*16+16) = col-tiles {w, w+4, w+8, w+12} (its units' i,f,g,o cols).
// Gate math fully in registers; xk gathered straight into MFMA C-init with
// one-step register prefetch; h double-buffered in LDS; ONE barrier/step.
// ---------------------------------------------------------------------------
__global__ __launch_bounds__(256) void lstm_kernel(const int*   __restrict__ tokens,
                                                   const float* __restrict__ embk,
                                                   const float* __restrict__ r1,
                                                   const float* __restrict__ Wd,
                                                   const float* __restrict__ bd,
                                                   float* __restrict__ out) {
    __shared__ int    tokLDS[16 * T_];       // 5.1 KB
    __shared__ __bf16 hbuf[2][16 * S_H];     // 2 x 2.3 KB

    const int tid  = threadIdx.x;
    const int lane = tid & 63;
    const int w    = tid >> 6;               // unit-chunk 0..3
    const int n    = lane & 15;
    const int kg   = lane >> 4;
    const int bb   = blockIdx.x * 16;
    const int cb   = w * 16 + n;             // this lane's unit column u

    // stage tokens (rows contiguous) + zero the t=0 read buffer (hbuf[1])
    for (int i = tid; i < 16 * T_; i += 256) tokLDS[i] = tokens[bb * T_ + i];
    for (int i = tid; i < 16 * S_H; i += 256) hbuf[1][i] = (__bf16)0.f;

    // r1 B-fragments for this wave's 4 col-tiles, 2 K-chunks, held in VGPRs.
    // B[k][col]: col = j*64 + cb, k = kc*32 + kg*8 + jj
    bf16x8 bfr[4][2];
#pragma unroll
    for (int j = 0; j < 4; ++j)
#pragma unroll
        for (int kc = 0; kc < 2; ++kc) {
            bf16x8 s;
#pragma unroll
            for (int jj = 0; jj < 8; ++jj)
                s[jj] = (__bf16)r1[(kc * 32 + kg * 8 + jj) * G_ + j * 64 + cb];
            bfr[j][kc] = s;
        }

    float c[4] = {0.f, 0.f, 0.f, 0.f};       // cell state: (b=kg*4+r, u=cb)
    float h[4] = {0.f, 0.f, 0.f, 0.f};

    __syncthreads();                         // tokens + h init visible

    // prefetch xk for t=0: xk[j][r] = embk[tok[b_r]][j*64+cb]  (C-layout)
    float xk[4][4];
    {
        int trow[4];
#pragma unroll
        for (int r = 0; r < 4; ++r) trow[r] = tokLDS[(kg * 4 + r) * T_ + 0];
#pragma unroll
        for (int j = 0; j < 4; ++j)
#pragma unroll
            for (int r = 0; r < 4; ++r)
                xk[j][r] = embk[(long)trow[r] * G_ + j * 64 + cb];
    }

    for (int t = 0; t < T_; ++t) {
        // A-fragments of h_{t-1}: A[m][k], m = n (batch), k = kg*8+jj
        const __bf16* hb = hbuf[(t + 1) & 1];
        bf16x8 a0 = *(const bf16x8*)(hb + n * S_H + kg * 8);
        bf16x8 a1 = *(const bf16x8*)(hb + n * S_H + 32 + kg * 8);

        // z = xk + h @ r1, per gate j, all in registers
        floatx4 acc[4];
#pragma unroll
        for (int j = 0; j < 4; ++j) {
            floatx4 a = {xk[j][0], xk[j][1], xk[j][2], xk[j][3]};
            a = __builtin_amdgcn_mfma_f32_16x16x32_bf16(a0, bfr[j][0], a, 0, 0, 0);
            a = __builtin_amdgcn_mfma_f32_16x16x32_bf16(a1, bfr[j][1], a, 0, 0, 0);
            acc[j] = a;
        }

        // prefetch next step's xk (window = gate math + barrier + A-read)
        if (t + 1 < T_) {
            int trow[4];
#pragma unroll
            for (int r = 0; r < 4; ++r) trow[r] = tokLDS[(kg * 4 + r) * T_ + t + 1];
#pragma unroll
            for (int j = 0; j < 4; ++j)
#pragma unroll
                for (int r = 0; r < 4; ++r)
                    xk[j][r] = embk[(long)trow[r] * G_ + j * 64 + cb];
        }

        // gates: 4 cells/lane (b=kg*4+r, u=cb), zi/zf/zg/zo same lane+reg
        __bf16* hw = hbuf[t & 1];
#pragma unroll
        for (int r = 0; r < 4; ++r) {
            float zi = acc[0][r], zf = acc[1][r], zg = acc[2][r], zo = acc[3][r];
            float cn = sigmoidf_(zf) * c[r] + sigmoidf_(zi) * tanhf_(zg);
            float hn = sigmoidf_(zo) * tanhf_(cn);
            c[r] = cn;
            h[r] = hn;
            hw[(kg * 4 + r) * S_H + cb] = (__bf16)hn;
        }

        __syncthreads();                     // h_t visible; also guards WAR on hbuf
    }

    // out[b] = sigmoid(h_final[b] . Wd + bd); h_79 lives in hbuf[1]
    if (tid < 16) {
        const __bf16* hb = hbuf[1] + tid * S_H;
        float s = bd[0];
#pragma unroll
        for (int u = 0; u < U_; ++u) s = fmaf((float)hb[u], Wd[u], s);
        out[bb + tid] = sigmoidf_(s);
    }
}

// ---------------------------------------------------------------------------
extern "C" void kernel_launch(void* const* d_in, const int* in_sizes, int n_in,
                              void* d_out, int out_size, void* d_ws, size_t ws_size,
                              hipStream_t stream) {
    const int*   tokens = (const int*)  d_in[0];
    const float* emb    = (const float*)d_in[1];
    // d_in[2..4] = k0, r0, b0 : dead in the reference (cell0 state unused)
    const float* k1     = (const float*)d_in[5];
    const float* r1     = (const float*)d_in[6];
    const float* b1     = (const float*)d_in[7];
    const float* Wd     = (const float*)d_in[8];
    const float* bd     = (const float*)d_in[9];
    float*       out    = (float*)d_out;

    float* embk = (float*)d_ws;              // V_*G_ floats = 10.24 MB

    embk_kernel<<<(V_ + 63) / 64, 256, 0, stream>>>(emb, k1, b1, embk);
    lstm_kernel<<<B_ / 16, 256, 0, stream>>>(tokens, embk, r1, Wd, bd, out);
}